// Round 3
// baseline (364.758 us; speedup 1.0000x reference)
//
#include <hip/hip_runtime.h>
#include <cstdint>
#include <cstddef>

// ---------------------------------------------------------------------------
// Transformer block on MI355X (gfx950), bf16 MFMA path.
// R11: gemm256 cross-phase pipeline — ds_reads issued one phase early
//      (consumed by the NEXT phase's MFMA), ONE barrier per phase, two
//      vmcnt(4) per K-tile (P2 and P4). LDS reads now overlap MFMA.
//      Plus L2-resident block mapping: per-XCD super-tiles (serpentine) so
//      each XCD's K-slice working set stays L2-hot.
//      attn/proj/LN unchanged from R10.
// ---------------------------------------------------------------------------

typedef unsigned short u16;
typedef short bf16x8 __attribute__((ext_vector_type(8)));
typedef float f32x4 __attribute__((ext_vector_type(4)));

#define C_EMBD 1024
#define T_SEQ  2048
#define N_BATCH 2
#define N_HEADS 16
#define HEAD_D 64
#define M_TOK  4096   // N_BATCH * T_SEQ
#define Q_SCALE 0.18033688011112042f  // 1/sqrt(64) * log2(e)

__device__ __forceinline__ u16 f2b(float f) {
  union { float f; unsigned u; } v; v.f = f;
  unsigned r = (v.u + 0x7fffu + ((v.u >> 16) & 1u)) >> 16;  // RNE
  return (u16)r;
}
__device__ __forceinline__ float b2f(u16 u) {
  union { unsigned u; float f; } v; v.u = ((unsigned)u) << 16;
  return v.f;
}
// pack 2 fp32 -> bf16x2 by truncation: lo16 = a.hi16, hi16 = b.hi16 (1 VALU op)
__device__ __forceinline__ unsigned pk2(float a, float b) {
  union { float f; unsigned u; } x, y; x.f = a; y.f = b;
  return __builtin_amdgcn_perm(y.u, x.u, 0x07060302u);
}
__device__ __forceinline__ void load_lds16(const void* g, void* l) {
  __builtin_amdgcn_global_load_lds(
      (const __attribute__((address_space(1))) void*)g,
      (__attribute__((address_space(3))) void*)l, 16, 0, 0);
}
// tanh-form GELU in exp2 domain: x * t/(t+1), t = exp2(2.3021859*(x+0.044715x^3))
__device__ __forceinline__ float gelu_fast(float x) {
  const float p = x * __builtin_fmaf(0.044715f * x, x, 1.0f);
  const float t = __builtin_amdgcn_exp2f(2.3021859215f * p);
  return x * t * __builtin_amdgcn_rcpf(t + 1.0f);
}

// ---------------------------------------------------------------------------
// Fused weight transpose + cast for all 4 weights: W[K][N] fp32 -> Wt[N][K] bf16
// ---------------------------------------------------------------------------
__global__ __launch_bounds__(256) void transpose_cast_all(
    const float* __restrict__ W0, u16* __restrict__ D0,   // attn 1024x3072
    const float* __restrict__ W1, u16* __restrict__ D1,   // proj 1024x1024
    const float* __restrict__ W2, u16* __restrict__ D2,   // fc   1024x4096
    const float* __restrict__ W3, u16* __restrict__ D3) { // fc2  4096x1024
  int id = blockIdx.x;
  const float* W; u16* D; int K, N, t;
  if (id < 3072)      { W = W0; D = D0; K = 1024; N = 3072; t = id; }
  else if (id < 4096) { W = W1; D = D1; K = 1024; N = 1024; t = id - 3072; }
  else if (id < 8192) { W = W2; D = D2; K = 1024; N = 4096; t = id - 4096; }
  else                { W = W3; D = D3; K = 4096; N = 1024; t = id - 8192; }
  const int nTN = N >> 5;
  const int n0 = (t % nTN) * 32, k0 = (t / nTN) * 32;
  __shared__ float tile[32][33];
  const int tx = threadIdx.x & 31, ty = threadIdx.x >> 5;  // ty in [0,8)
#pragma unroll
  for (int i = 0; i < 32; i += 8)
    tile[ty + i][tx] = W[(size_t)(k0 + ty + i) * N + n0 + tx];
  __syncthreads();
#pragma unroll
  for (int i = 0; i < 32; i += 8)
    D[(size_t)(n0 + ty + i) * K + k0 + tx] = f2b(tile[tx][ty + i]);
}

// ---------------------------------------------------------------------------
// LayerNorm over rows of 1024 fp32 -> bf16 out. One block (256 thr) per row.
// ---------------------------------------------------------------------------
__global__ __launch_bounds__(256) void ln_cast(
    const float* __restrict__ X, const float* __restrict__ g,
    const float* __restrict__ b, u16* __restrict__ Y) {
  const int row = blockIdx.x;
  const int tid = threadIdx.x;
  const float4 v = ((const float4*)(X + (size_t)row * C_EMBD))[tid];
  float s = v.x + v.y + v.z + v.w;
  float ss = v.x * v.x + v.y * v.y + v.z * v.z + v.w * v.w;
#pragma unroll
  for (int off = 32; off > 0; off >>= 1) {
    s += __shfl_down(s, off, 64);
    ss += __shfl_down(ss, off, 64);
  }
  __shared__ float red[8];
  __shared__ float stats[2];
  const int wave = tid >> 6, lane = tid & 63;
  if (lane == 0) { red[wave] = s; red[4 + wave] = ss; }
  __syncthreads();
  if (tid == 0) {
    float S = red[0] + red[1] + red[2] + red[3];
    float SS = red[4] + red[5] + red[6] + red[7];
    float mu = S * (1.0f / C_EMBD);
    float var = SS * (1.0f / C_EMBD) - mu * mu;
    stats[0] = mu;
    stats[1] = rsqrtf(var + 1e-5f);
  }
  __syncthreads();
  const float mu = stats[0], rs = stats[1];
  const float4 gv = ((const float4*)g)[tid];
  const float4 bv = ((const float4*)b)[tid];
  ushort4 o;
  o.x = f2b((v.x - mu) * rs * gv.x + bv.x);
  o.y = f2b((v.y - mu) * rs * gv.y + bv.y);
  o.z = f2b((v.z - mu) * rs * gv.z + bv.z);
  o.w = f2b((v.w - mu) * rs * gv.w + bv.w);
  ((ushort4*)(Y + (size_t)row * C_EMBD))[tid] = o;
}

// ---------------------------------------------------------------------------
// Fused: x1 = P0 + P1 + bias + res, then LayerNorm(x1) -> bf16 Y.
// ---------------------------------------------------------------------------
__global__ __launch_bounds__(256) void ln_reduce_cast(
    const float* __restrict__ P0, const float* __restrict__ P1,
    const float* __restrict__ bias, const float* __restrict__ res,
    const float* __restrict__ g, const float* __restrict__ b,
    float* __restrict__ X1, u16* __restrict__ Y) {
  const int row = blockIdx.x;
  const int tid = threadIdx.x;
  const size_t base = (size_t)row * C_EMBD;
  const float4 p0 = ((const float4*)(P0 + base))[tid];
  const float4 p1 = ((const float4*)(P1 + base))[tid];
  const float4 rr = ((const float4*)(res + base))[tid];
  const float4 bb = ((const float4*)bias)[tid];
  float4 v;
  v.x = p0.x + p1.x + rr.x + bb.x;
  v.y = p0.y + p1.y + rr.y + bb.y;
  v.z = p0.z + p1.z + rr.z + bb.z;
  v.w = p0.w + p1.w + rr.w + bb.w;
  ((float4*)(X1 + base))[tid] = v;
  float s = v.x + v.y + v.z + v.w;
  float ss = v.x * v.x + v.y * v.y + v.z * v.z + v.w * v.w;
#pragma unroll
  for (int off = 32; off > 0; off >>= 1) {
    s += __shfl_down(s, off, 64);
    ss += __shfl_down(ss, off, 64);
  }
  __shared__ float red[8];
  __shared__ float stats[2];
  const int wave = tid >> 6, lane = tid & 63;
  if (lane == 0) { red[wave] = s; red[4 + wave] = ss; }
  __syncthreads();
  if (tid == 0) {
    float S = red[0] + red[1] + red[2] + red[3];
    float SS = red[4] + red[5] + red[6] + red[7];
    float mu = S * (1.0f / C_EMBD);
    float var = SS * (1.0f / C_EMBD) - mu * mu;
    stats[0] = mu;
    stats[1] = rsqrtf(var + 1e-5f);
  }
  __syncthreads();
  const float mu = stats[0], rs = stats[1];
  const float4 gv = ((const float4*)g)[tid];
  const float4 bv = ((const float4*)b)[tid];
  ushort4 o;
  o.x = f2b((v.x - mu) * rs * gv.x + bv.x);
  o.y = f2b((v.y - mu) * rs * gv.y + bv.y);
  o.z = f2b((v.z - mu) * rs * gv.z + bv.z);
  o.w = f2b((v.w - mu) * rs * gv.w + bv.w);
  ((ushort4*)(Y + base))[tid] = o;
}

enum { EPI_BF16 = 0, EPI_GELU_BF16 = 2, EPI_PART = 3, EPI_QKV = 4 };

// ---------------------------------------------------------------------------
// OLD 128x128 GEMM (2-barrier structure) — kept for proj only (split-K=2).
// ---------------------------------------------------------------------------
template <int EPI, int SPLIT>
__global__ __launch_bounds__(256) void gemm_bt(
    const u16* __restrict__ A, const u16* __restrict__ Bt,
    const float* __restrict__ bias,
    void* __restrict__ Cout, void* __restrict__ Cout2, void* __restrict__ Cout3,
    int M, int N, int K) {
  __shared__ u16 As[128 * 64];
  __shared__ u16 Bs[128 * 64];
  const int tid = threadIdx.x;
  const int wave = tid >> 6, lane = tid & 63;
  const int quad = lane >> 4, l16 = lane & 15;
  const int sw = l16 & 7;

  const int id = (int)blockIdx.y * (int)gridDim.x + (int)blockIdx.x;
  const int mt = ((id & 7) << 2) + ((id >> 3) & 3);
  const int nt_ = id >> 5;
  const int m0 = mt * 128, n0 = nt_ * 128;

  const int wm = (wave >> 1) * 64, wn = (wave & 1) * 64;

  f32x4 acc[4][4] = {};

  size_t aOff[4], bOff[4];
  int ldsOff[4];
#pragma unroll
  for (int i = 0; i < 4; ++i) {
    const int c = tid + i * 256;
    const int row = c >> 3, gc = ((c & 7) ^ (row & 7)) * 8;
    aOff[i] = (size_t)(m0 + row) * K + gc;
    bOff[i] = (size_t)(n0 + row) * K + gc;
    ldsOff[i] = c * 8;
  }

  const int kTiles = (K >> 6) / SPLIT;
  const int kt0 = (SPLIT == 2) ? (int)blockIdx.z * kTiles : 0;
  for (int kt = kt0; kt < kt0 + kTiles; ++kt) {
    const int k0 = kt << 6;
#pragma unroll
    for (int i = 0; i < 4; ++i)
      load_lds16(A + aOff[i] + k0, &As[ldsOff[i]]);
#pragma unroll
    for (int i = 0; i < 4; ++i)
      load_lds16(Bt + bOff[i] + k0, &Bs[ldsOff[i]]);
    __syncthreads();
#pragma unroll
    for (int ks = 0; ks < 2; ++ks) {
      bf16x8 aF[4], bF[4];
#pragma unroll
      for (int t = 0; t < 4; ++t) {
        aF[t] = *(const bf16x8*)
            &As[(wm + t * 16 + l16) * 64 + (((ks * 4 + quad) ^ sw) * 8)];
        bF[t] = *(const bf16x8*)
            &Bs[(wn + t * 16 + l16) * 64 + (((ks * 4 + quad) ^ sw) * 8)];
      }
#pragma unroll
      for (int tm = 0; tm < 4; ++tm)
#pragma unroll
        for (int tn = 0; tn < 4; ++tn)
          acc[tm][tn] = __builtin_amdgcn_mfma_f32_16x16x32_bf16(
              bF[tn], aF[tm], acc[tm][tn], 0, 0, 0);  // transposed: C^T
    }
    __syncthreads();
  }

  float* Pz = (float*)((SPLIT == 2 && blockIdx.z == 1) ? Cout2 : Cout);
#pragma unroll
  for (int tm = 0; tm < 4; ++tm) {
    const int row = m0 + wm + tm * 16 + l16;
#pragma unroll
    for (int tn = 0; tn < 4; ++tn) {
      const int col = n0 + wn + tn * 16 + quad * 4;
      if constexpr (EPI == EPI_PART) {
        *(float4*)&Pz[(size_t)row * N + col] = *(float4*)&acc[tm][tn];
      } else {
        const float4 bz = *(const float4*)&bias[col];
        float v0 = acc[tm][tn][0] + bz.x, v1 = acc[tm][tn][1] + bz.y;
        float v2 = acc[tm][tn][2] + bz.z, v3 = acc[tm][tn][3] + bz.w;
        if constexpr (EPI == EPI_GELU_BF16) {
          v0 = gelu_fast(v0); v1 = gelu_fast(v1);
          v2 = gelu_fast(v2); v3 = gelu_fast(v3);
        }
        ushort4 o;
        o.x = f2b(v0); o.y = f2b(v1); o.z = f2b(v2); o.w = f2b(v3);
        *(ushort4*)&((u16*)Cout)[(size_t)row * N + col] = o;
      }
    }
  }
}

// ---------------------------------------------------------------------------
// 256x256 pipelined 4-phase GEMM. 512 thr / 8 waves (2Mx4N), BK=64, 128 KiB.
// Cross-phase pipeline: each phase ISSUES the ds_reads consumed by the NEXT
// phase's MFMA, so the LDS burst overlaps this phase's MFMA. One s_barrier
// per phase. Compiler inserts counted lgkmcnt for the read->MFMA deps.
//   P1: read B1[p]->bF1   | stage A1[p^1](k1) | MFMA(0,0)=aF0*bF0 | bar
//   P2: read A1[p]->aF1   | stage B1[p^1](k1) | MFMA(0,1)=aF0*bF1 | vm4 bar
//   P3: read A0[p^1]->aF0 | stage A0[p](k2)   | MFMA(1,0)=aF1*bF0 | bar
//   P4: read B0[p^1]->bF0 | stage B0[p](k2)   | MFMA(1,1)=aF1*bF1 | vm4 bar
// Ledger (2 loads/stage): vm4@P2(t) retires t-1's P3,P4 stages (= A0/B0
// slots read at P3/P4(t)); vm4@P4(t) retires t's P1,P2 (= A1/B1 slots read
// at P1/P2(t+1)). Steady outstanding after each vm4 = 4. Never vmcnt(0).
// WAR: every slot has >=2 barriers between its read-drain and restage.
// ---------------------------------------------------------------------------
#define G_LOADA(DST, MQ, PAR)                                                 \
  { const u16* Ab_ = &lds[(unsigned)((((MQ)*2 + (PAR))) << 13)];              \
    _Pragma("unroll") for (int t_ = 0; t_ < 4; ++t_)                          \
      _Pragma("unroll") for (int ks = 0; ks < 2; ++ks)                        \
        DST[t_][ks] = *(const bf16x8*)&Ab_[(wm * 64 + t_ * 16 + l16) * 64 +   \
                                           (((ks * 4 + quad) ^ sw) << 3)]; }
#define G_LOADB(DST, NQ, PAR)                                                 \
  { const u16* Bb_ = &lds[(unsigned)(((2 + (NQ)) * 2 + (PAR)) << 13)];        \
    _Pragma("unroll") for (int u_ = 0; u_ < 2; ++u_)                          \
      _Pragma("unroll") for (int ks = 0; ks < 2; ++ks)                        \
        DST[u_][ks] = *(const bf16x8*)&Bb_[(wn * 32 + u_ * 16 + l16) * 64 +   \
                                           (((ks * 4 + quad) ^ sw) << 3)]; }
#define G_MMA(MQ, NQ, AV, BV)                                                 \
    _Pragma("unroll") for (int t_ = 0; t_ < 4; ++t_)                          \
      _Pragma("unroll") for (int u_ = 0; u_ < 2; ++u_)                        \
        _Pragma("unroll") for (int ks = 0; ks < 2; ++ks)                      \
          acc[(MQ)*4 + t_][(NQ)*2 + u_] =                                     \
              __builtin_amdgcn_mfma_f32_16x16x32_bf16(                        \
                  BV[u_][ks], AV[t_][ks], acc[(MQ)*4 + t_][(NQ)*2 + u_],      \
                  0, 0, 0);
#define G_BAR()   __builtin_amdgcn_s_barrier()
#define G_VM4()   asm volatile("s_waitcnt vmcnt(4)" ::: "memory")
#define G_PRIO(x) __builtin_amdgcn_s_setprio(x)

template <int EPI, int SPLIT>
__global__ __launch_bounds__(512, 2) void gemm256(
    const u16* __restrict__ A, const u16* __restrict__ Bt,
    const float* __restrict__ bias,
    void* __restrict__ Cout, void* __restrict__ Cout2,
    void* __restrict__ Cout3, void* __restrict__ Cout4,
    int M, int N, int K) {
  __shared__ u16 lds[8 * 8192];  // 8 regions x 16 KB = 128 KiB
  const int tid = threadIdx.x;
  const int lane = tid & 63;
  const int wave = tid >> 6;
  const int quad = lane >> 4, l16 = lane & 15;
  const int sw = l16 & 7;
  const int wm = wave >> 2, wn = wave & 3;  // 2 x 4 wave grid; 128x64 / wave

  // L2-resident mapping: per-XCD super-tile of am x bn tiles (serpentine
  // ntl walk). All blocks of an XCD are co-resident; per-K-slice footprint
  // (am+bn)*32KB << 4MB L2, and each slab is fetched from L3 once per XCD.
  const int nTM = M >> 8, nTN = N >> 8;
  const int xcd = (int)blockIdx.x & 7;
  const int s = (int)blockIdx.x >> 3;       // slot within XCD
  const int gn = (nTN >= 6) ? 2 : 1;        // XCD grid over (mt,ntl) chunks
  const int gm = 8 / gn;
  const int am = nTM / gm, bn = nTN / gn;
  const int bi = s / am;
  int ai = s % am;
  if (bi & 1) ai = am - 1 - ai;             // serpentine
  const int mt = (xcd % gm) * am + ai;
  const int ntl = (xcd / gm) * bn + bi;
  const int m0 = mt << 8, n0 = ntl << 8;

  f32x4 acc[8][4] = {};  // acc[TM][TN]: m = m0+wm*128+TM*16+l16,
                         //             n = n0+wn*64+TN*16+quad*4+r

  // staging geometry: chunk c -> LDS row c>>3, source col chunk (c&7)^(r&7)
  size_t aOffs[2][2], bOffs[2][2];
  int ldsc[2];
#pragma unroll
  for (int i = 0; i < 2; ++i) {
    const int c = tid + i * 512;
    const int r = c >> 3;
    const int scc = ((c & 7) ^ (r & 7)) << 3;
    ldsc[i] = c * 8;
    const int ra = ((r >> 6) << 7) + (r & 63);  // A: X rows {0-63,128-191}
    const int rb = ((r >> 5) << 6) + (r & 31);  // B: quadrant-major rows
    aOffs[0][i] = (size_t)(m0 + ra) * K + scc;
    aOffs[1][i] = (size_t)(m0 + ra + 64) * K + scc;
    bOffs[0][i] = (size_t)(n0 + rb) * K + scc;
    bOffs[1][i] = (size_t)(n0 + rb + 32) * K + scc;
  }
  auto stA = [&](int mq, int p, int kt) {
    u16* dst = &lds[(size_t)((mq * 2 + p) << 13)];
    const int k0 = kt << 6;
#pragma unroll
    for (int i = 0; i < 2; ++i)
      load_lds16(A + aOffs[mq][i] + k0, dst + ldsc[i]);
  };
  auto stB = [&](int nq, int p, int kt) {
    u16* dst = &lds[(size_t)(((2 + nq) * 2 + p) << 13)];
    const int k0 = kt << 6;
#pragma unroll
    for (int i = 0; i < 2; ++i)
      load_lds16(Bt + bOffs[nq][i] + k0, dst + ldsc[i]);
  };

  const int NT = (K >> 6) / SPLIT;  // 16 for all our shapes (even)
  const int kt0 = (SPLIT > 1) ? (int)blockIdx.z * NT : 0;

  bf16x8 aF0[4][2], aF1[4][2];   // carried A fragments (two M-halves)
  bf16x8 bF0[2][2], bF1[2][2];   // carried B fragments (two N-quadrants)

  // prologue: {A1,B1,A0,B0}(t0,par0) then {A0,B0}(t1,par1).
  // vmcnt(4) retires the first 4 stage-calls; leaves {A0,B0}[par1] = ledger.
  stA(1, 0, kt0); stB(1, 0, kt0); stA(0, 0, kt0); stB(0, 0, kt0);
  stA(0, 1, kt0 + 1); stB(0, 1, kt0 + 1);
  G_VM4();
  G_BAR();
  G_LOADA(aF0, 0, 0);
  G_LOADB(bF0, 0, 0);

  for (int t = 0; t < NT; t += 2) {
#pragma unroll
    for (int p = 0; p < 2; ++p) {
      const int par = p;
      const int k1 = kt0 + (t + 1 + p < NT ? t + 1 + p : 0);  // junk on wrap
      const int k2 = kt0 + (t + 2 + p < NT ? t + 2 + p : 0);
      // P1
      G_LOADB(bF1, 1, par);
      stA(1, par ^ 1, k1);
      G_PRIO(1); G_MMA(0, 0, aF0, bF0); G_PRIO(0);
      G_BAR();
      // P2
      G_LOADA(aF1, 1, par);
      stB(1, par ^ 1, k1);
      G_PRIO(1); G_MMA(0, 1, aF0, bF1); G_PRIO(0);
      G_VM4();
      G_BAR();
      // P3
      G_LOADA(aF0, 0, par ^ 1);
      stA(0, par, k2);
      G_PRIO(1); G_MMA(1, 0, aF1, bF0); G_PRIO(0);
      G_BAR();
      // P4
      G_LOADB(bF0, 0, par ^ 1);
      stB(0, par, k2);
      G_PRIO(1); G_MMA(1, 1, aF1, bF1); G_PRIO(0);
      G_VM4();
      G_BAR();
    }
  }
  // drain LDS-DMA before epilogue
  asm volatile("s_waitcnt vmcnt(0)" ::: "memory");

  if constexpr (EPI == EPI_PART) {
    const int z = (SPLIT > 1) ? (int)blockIdx.z : 0;
    float* Pz = (float*)(z == 0 ? Cout : z == 1 ? Cout2
                                       : z == 2 ? Cout3 : Cout4);
#pragma unroll
    for (int tm = 0; tm < 8; ++tm) {
      const int row = m0 + wm * 128 + tm * 16 + l16;
#pragma unroll
      for (int tn = 0; tn < 4; ++tn) {
        const int col = n0 + wn * 64 + tn * 16 + quad * 4;
        *(float4*)&Pz[(size_t)row * N + col] = *(float4*)&acc[tm][tn];
      }
    }
  } else if constexpr (EPI == EPI_QKV) {
#pragma unroll
    for (int tm = 0; tm < 8; ++tm) {
      const int row = m0 + wm * 128 + tm * 16 + l16;
      const int bb = row >> 11, tt = row & (T_SEQ - 1);
#pragma unroll
      for (int tn = 0; tn < 4; ++tn) {
        const int col = n0 + wn * 64 + tn * 16 + quad * 4;
        const float4 bz = *(const float4*)&bias[col];
        float v0 = acc[tm][tn][0] + bz.x, v1 = acc[tm][tn][1] + bz.y;
        float v2 = acc[tm][tn][2] + bz.z, v3 = acc[tm][tn][3] + bz.w;
        const int sec = col >> 10;
        const int h = (col & 1023) >> 6, d4 = col & 63;
        const int bh = bb * N_HEADS + h;
        if (sec == 0) {                      // Q, pre-scaled
          ushort4 o;
          o.x = f2b(v0 * Q_SCALE); o.y = f2b(v1 * Q_SCALE);
          o.z = f2b(v2 * Q_SCALE); o.w = f2b(v3 * Q_SCALE);
          *(ushort4*)&((u16*)Cout)[((size_t)bh * T_SEQ + tt) * HEAD_D + d4] = o;
        } else if (sec == 1) {               // K
          ushort4 o;
          o.x = f2b(v0); o.y = f2b(v1); o.z = f2b(v2); o.w = f2b(v3);
          *(ushort4*)&((u16*)Cout2)[((size_t)bh * T_SEQ + tt) * HEAD_D + d4] = o;
        } else {                             // V^T: [bh][d][t]
          u16* vp = (u16*)Cout3 + ((size_t)bh * HEAD_D + d4) * T_SEQ + tt;
          vp[0] = f2b(v0); vp[T_SEQ] = f2b(v1);
          vp[2 * T_SEQ] = f2b(v2); vp[3 * T_SEQ] = f2b(v3);
        }
      }
    }
  } else {  // EPI_BF16 / EPI_GELU_BF16
#pragma unroll
    for (int tm = 0; tm < 8; ++tm) {
      const int row = m0 + wm * 128 + tm * 16 + l16;
#pragma unroll
      for (int tn = 0; tn < 4; ++tn) {
        const int col = n0 + wn * 64 + tn * 16 + quad * 4;
        const float4 bz = *(const float4*)&bias[col];
        float v0 = acc[tm][tn][0] + bz.x, v1 = acc[tm][tn][1] + bz.y;
        float v2 = acc[tm][tn][2] + bz.z, v3 = acc[tm][tn][3] + bz.w;
        if constexpr (EPI == EPI_GELU_BF16) {
          v0 = gelu_fast(v0); v1 = gelu_fast(v1);
          v2 = gelu_fast(v2); v3 = gelu_fast(v3);
        }
        ushort4 o;
        o.x = f2b(v0); o.y = f2b(v1); o.z = f2b(v2); o.w = f2b(v3);
        *(ushort4*)&((u16*)Cout)[(size_t)row * N + col] = o;
      }
    }
  }
}

// ---------------------------------------------------------------------------
// reduce4: out = P0 + P1 + P2 + P3 + bias[col] + res. float4 per thread.
// ---------------------------------------------------------------------------
__global__ __launch_bounds__(256) void reduce_add4(
    const float* __restrict__ P0, const float* __restrict__ P1,
    const float* __restrict__ P2, const float* __restrict__ P3,
    const float* __restrict__ bias, const float* __restrict__ res,
    float* __restrict__ out) {
  const int idx = blockIdx.x * 256 + threadIdx.x;  // float4 index
  const float4 a = ((const float4*)P0)[idx];
  const float4 b = ((const float4*)P1)[idx];
  const float4 c = ((const float4*)P2)[idx];
  const float4 d = ((const float4*)P3)[idx];
  const float4 r = ((const float4*)res)[idx];
  const float4 g = ((const float4*)bias)[idx & 255];  // 1024/4 = 256
  float4 o;
  o.x = a.x + b.x + c.x + d.x + r.x + g.x;
  o.y = a.y + b.y + c.y + d.y + r.y + g.y;
  o.z = a.z + b.z + c.z + d.z + r.z + g.z;
  o.w = a.w + b.w + c.w + d.w + r.w + g.w;
  ((float4*)out)[idx] = o;
}

// ---------------------------------------------------------------------------
// Flash attention (causal). 1024 single-q-tile blocks, heavy-qb-first per
// XCD; defer-max (THR=8); LDS 40960 B = 4 blocks/CU.
// ---------------------------------------------------------------------------
__global__ __launch_bounds__(256, 4) void attn_fwd(
    const u16* __restrict__ Q, const u16* __restrict__ Kb,
    const u16* __restrict__ Vt, u16* __restrict__ Y) {
  const int id = (int)blockIdx.x;
  const int xcd = id & 7, slot = id >> 3;
  const int bh = xcd + ((slot & 3) << 3);       // 4 heads per XCD
  const int qb = (T_SEQ / 64 - 1) - (slot >> 2);  // heavy blocks dispatch first
  const int tid = threadIdx.x;
  const int wave = tid >> 6, lane = tid & 63;
  const int quad = lane >> 4, l16 = lane & 15;
  const int sw = l16 & 7;  // xor-swizzle key for frag reads
  const u16* Qp = Q + (size_t)bh * T_SEQ * HEAD_D;
  const u16* Kp = Kb + (size_t)bh * T_SEQ * HEAD_D;
  const u16* Vp = Vt + (size_t)bh * HEAD_D * T_SEQ;

  __shared__ u16 Ks[2][64 * 64];   // 16 KB
  __shared__ u16 Vs[2][64 * 64];   // 16 KB
  __shared__ u16 Pl[4][16 * 64];   // 8 KB, xor-swizzled chunks

  // staging geometry (chunk c -> row c>>3, col8 (c&7)^(row&7))
  const int c1 = tid, c2 = tid + 256;
  const int r1 = c1 >> 3, g1 = ((c1 & 7) ^ (r1 & 7)) * 8;
  const int r2 = c2 >> 3, g2 = ((c2 & 7) ^ (r2 & 7)) * 8;
  const size_t kO1 = (size_t)r1 * HEAD_D + g1, kO2 = (size_t)r2 * HEAD_D + g2;
  const size_t vO1 = (size_t)r1 * T_SEQ + g1, vO2 = (size_t)r2 * T_SEQ + g2;
  u16* const dK1[2] = {&Ks[0][c1 * 8], &Ks[1][c1 * 8]};
  u16* const dK2[2] = {&Ks[0][c2 * 8], &Ks[1][c2 * 8]};
  u16* const dV1[2] = {&Vs[0][c1 * 8], &Vs[1][c1 * 8]};
  u16* const dV2[2] = {&Vs[0][c2 * 8], &Vs[1][c2 * 8]};

  auto stageK = [&](int bb, int k0) {
    const u16* base = Kp + (size_t)k0 * HEAD_D;
    load_lds16(base + kO1, dK1[bb]);
    load_lds16(base + kO2, dK2[bb]);
  };
  auto stageV = [&](int bb, int k0) {
    const u16* base = Vp + k0;
    load_lds16(base + vO1, dV1[bb]);
    load_lds16(base + vO2, dV2[bb]);
  };

  const int b = bh >> 4, h = bh & 15;
  const int q0 = qb * 64;
  const int qglob = q0 + wave * 16 + l16;  // this lane's q row

  bf16x8 qF[2];
  qF[0] = *(const bf16x8*)&Qp[(size_t)qglob * HEAD_D + quad * 8];
  qF[1] = *(const bf16x8*)&Qp[(size_t)qglob * HEAD_D + 32 + quad * 8];

  f32x4 o[4] = {};   // O^T: d = nt*16 + quad*4 + r, q = l16
  float mrun = -3e38f, lrun = 0.0f;

  stageK(0, 0);
  stageV(0, 0);

  int buf = 0;
  for (int kb = 0; kb <= qb; ++kb) {
    const int k0 = kb * 64;
    __syncthreads();  // drains DMA + all waves' prior-buffer reads
    if (kb < qb) {
      stageK(buf ^ 1, k0 + 64);
      stageV(buf ^ 1, k0 + 64);
    }
    // S^T: key = nt*16 + quad*4 + r (rows), q = l16 (cols)
    f32x4 st[4] = {};
#pragma unroll
    for (int ks = 0; ks < 2; ++ks) {
#pragma unroll
      for (int nt = 0; nt < 4; ++nt) {
        bf16x8 kF = *(const bf16x8*)
            &Ks[buf][(nt * 16 + l16) * 64 + (((ks * 4 + quad) ^ sw) * 8)];
        st[nt] = __builtin_amdgcn_mfma_f32_16x16x32_bf16(kF, qF[ks], st[nt],
                                                         0, 0, 0);
      }
    }
    if (kb == qb) {  // causal mask, diagonal tile only
#pragma unroll
      for (int nt = 0; nt < 4; ++nt) {
#pragma unroll
        for (int r = 0; r < 4; ++r) {
          const int key = k0 + nt * 16 + quad * 4 + r;
          if (key > qglob) st[nt][r] = -3e38f;
        }
      }
    }
    // per-row tile max (register tree + cross-quad lanes ^16,^32)
    float m = st[0][0];
#pragma unroll
    for (int nt = 0; nt < 4; ++nt)
#pragma unroll
      for (int r = 0; r < 4; ++r) m = fmaxf(m, st[nt][r]);
    m = fmaxf(m, __shfl_xor(m, 16, 64));
    m = fmaxf(m, __shfl_xor(m, 32, 64));
    // defer-max (T13): skip rescale while growth <= 8 (P bounded by 2^8)
    if (!__all(m - mrun <= 8.0f)) {
      const float nm = fmaxf(mrun, m);
      const float alpha = __builtin_amdgcn_exp2f(mrun - nm);
      mrun = nm;
      lrun *= alpha;
#pragma unroll
      for (int nt = 0; nt < 4; ++nt)
#pragma unroll
        for (int r = 0; r < 4; ++r) o[nt][r] *= alpha;
    }
    float sum = 0.0f;
#pragma unroll
    for (int nt = 0; nt < 4; ++nt)
#pragma unroll
      for (int r = 0; r < 4; ++r) {
        const float p = __builtin_amdgcn_exp2f(st[nt][r] - mrun);
        st[nt][r] = p;
        sum += p;
      }
    sum += __shfl_xor(sum, 16, 64);
    sum += __shfl_xor(sum, 32, 64);
    lrun += sum;
    // P^T -> LDS (swizzled): logical col = key idx; chunk (col>>3) ^ sw
#pragma unroll
    for (int nt = 0; nt < 4; ++nt) {
      uint2 pk;
      pk.x = pk2(st[nt][0], st[nt][1]);
      pk.y = pk2(st[nt][2], st[nt][3]);
      const int wc = (((2 * nt + (quad >> 1)) ^ sw) << 3) + ((quad & 1) << 2);
      *(uint2*)&Pl[wave][(l16 << 6) + wc] = pk;
    }
    // O^T += V^T P^T  (A = V^T from Vs, B = P^T from Pl)
#pragma unroll
    for (int ks = 0; ks < 2; ++ks) {
      bf16x8 aP = *(const bf16x8*)
          &Pl[wave][(l16 << 6) + (((ks * 4 + quad) ^ sw) << 3)];
#pragma unroll
      for (int nt = 0; nt < 4; ++nt) {
        bf16x8 vF = *(const bf16x8*)
            &Vs[buf][(nt * 16 + l16) * 64 + (((ks * 4 + quad) ^ sw) * 8)];
        o[nt] =
            __builtin_amdgcn_mfma_f32_16x16x32_bf16(vF, aP, o[nt], 0, 0, 0);
      }
    }
    buf ^= 1;
  }

  // write O^T / l -> Y bf16 [B,T,C]: row = token (l16), cols = d
  const float rl = 1.0f / lrun;
  u16* yp = Y + ((size_t)(b * T_SEQ + qglob)) * C_EMBD + h * HEAD_D;
#pragma unroll
  for (int nt = 0; nt < 4; ++nt) {
    ushort4 ov;
    ov.x = f2b(o[nt][0] * rl); ov.y = f2b(o[nt][1] * rl);
    ov.z = f2b(o[nt][2] * rl); ov.w = f2b(o[nt][3] * rl);
    *(ushort4*)&yp[nt * 16 + quad * 4] = ov;
  }
}

// ---------------------------------------------------------------------------
// Host side. Workspace layout (unchanged): 48 MB contiguous region dead by
// fc2 time for 3 split-K partials.
// ---------------------------------------------------------------------------
extern "C" void kernel_launch(void* const* d_in, const int* in_sizes, int n_in,
                              void* d_out, int out_size, void* d_ws,
                              size_t ws_size, hipStream_t stream) {
  const float* x      = (const float*)d_in[0];
  const float* W_attn = (const float*)d_in[1];
  const float* b_attn = (const float*)d_in[2];
  const float* W_proj = (const float*)d_in[3];
  const float* b_proj = (const float*)d_in[4];
  const float* W_fc   = (const float*)d_in[5];
  const float* b_fc   = (const float*)d_in[6];
  const float* W_fc2  = (const float*)d_in[7];
  const float* b_fc2  = (const float*)d_in[8];
  const float* ln1_g  = (const float*)d_in[9];
  const float* ln1_b  = (const float*)d_in[10];
  const float* ln2_g  = (const float*)d_in[11];
  const float* ln2_b  = (const float*)d_in[12];

  u16* wfc2T = (u16*)d_ws;                              // [1024][4096] bf16
  float* x1  = (float*)(wfc2T + (size_t)1024 * 4096);   // [4096][1024] f32
  u16* hbuf  = (u16*)(x1 + (size_t)M_TOK * C_EMBD);     // [4096][4096] bf16
  u16* dead  = hbuf + (size_t)M_TOK * 4096;             // 48 MB dead-at-fc2
  u16* wqkvT = dead;                                    // [3072][1024]
  u16* wprojT = wqkvT + (size_t)3072 * 1024;            // [1024][1024]
  u16* wfcT  = wprojT + (size_t)1024 * 1024;            // [4096][1024]
  u16* Abuf  = wfcT + (size_t)4096 * 1024;              // [4096][1024] bf16
  u16* Qb    = Abuf + (size_t)M_TOK * C_EMBD;           // [32][2048][64]
  u16* Kbuf  = Qb + (size_t)32 * T_SEQ * HEAD_D;
  u16* Vtb   = Kbuf + (size_t)32 * T_SEQ * HEAD_D;

  float* projP = (float*)hbuf;            // proj partials 2x16MB (dead window)
  float* fc2P1 = (float*)dead;            // over wqkvT..wfcT   (16 MB)
  float* fc2P2 = fc2P1 + (size_t)M_TOK * C_EMBD;  // over Abuf..Qb (16 MB)
  float* fc2P3 = fc2P2 + (size_t)M_TOK * C_EMBD;  // over Kbuf..Vtb (16 MB)

  const dim3 blk(256);
  const dim3 blk512(512);

  transpose_cast_all<<<12288, blk, 0, stream>>>(
      W_attn, wqkvT, W_proj, wprojT, W_fc, wfcT, W_fc2, wfc2T);

  ln_cast<<<M_TOK, blk, 0, stream>>>(x, ln1_g, ln1_b, Abuf);

  // qkv: 256^2 pipelined, grid 16*12 = 192
  gemm256<EPI_QKV, 1><<<dim3(192), blk512, 0, stream>>>(
      Abuf, wqkvT, b_attn, Qb, Kbuf, Vtb, nullptr, M_TOK, 3072, 1024);

  attn_fwd<<<dim3(1024), blk, 0, stream>>>(Qb, Kbuf, Vtb, Abuf);

  // proj: old 128^2 split-K=2 path (small GEMM; 256^2 can't fill the grid)
  gemm_bt<EPI_PART, 2><<<dim3(1024 / 128, M_TOK / 128, 2), blk, 0, stream>>>(
      Abuf, wprojT, nullptr, projP, projP + (size_t)M_TOK * C_EMBD, nullptr,
      M_TOK, 1024, 1024);
  ln_reduce_cast<<<M_TOK, blk, 0, stream>>>(
      projP, projP + (size_t)M_TOK * C_EMBD, b_proj, x, ln2_g, ln2_b,
      x1, Abuf);

  // fc: 256^2 pipelined, grid 16*16 = 256 (perfect fit)
  gemm256<EPI_GELU_BF16, 1><<<dim3(256), blk512, 0, stream>>>(
      Abuf, wfcT, b_fc, hbuf, nullptr, nullptr, nullptr, M_TOK, 4096, 1024);

  // fc2: 256^2 pipelined, split-K=4 -> grid 64*4 = 256; f32 partials
  gemm256<EPI_PART, 4><<<dim3(64, 1, 4), blk512, 0, stream>>>(
      hbuf, wfc2T, nullptr, d_out, fc2P1, fc2P2, fc2P3, M_TOK, 1024, 4096);
  reduce_add4<<<M_TOK * C_EMBD / 1024, blk, 0, stream>>>(
      (const float*)d_out, fc2P1, fc2P2, fc2P3, b_fc2, x1, (float*)d_out);
}

// Round 4
// 316.637 us; speedup vs baseline: 1.1520x; 1.1520x over previous
//
#include <hip/hip_runtime.h>
#include <cstdint>
#include <cstddef>

// ---------------------------------------------------------------------------
// Transformer block on MI355X (gfx950), bf16 MFMA path.
// R12: recombination round. gemm256 = R10's verified 8-phase schedule
//      (two barriers/phase, lgkmcnt(0)+setprio MFMA cluster, ONE vmcnt(4)
//      per K-tile at P4) + R11's serpentine per-XCD L2-resident mapping
//      (measured FETCH 78->27 MB). The R11 one-barrier pipeline is reverted
//      (measured -33%). attn/proj/LN unchanged.
// ---------------------------------------------------------------------------

typedef unsigned short u16;
typedef short bf16x8 __attribute__((ext_vector_type(8)));
typedef float f32x4 __attribute__((ext_vector_type(4)));

#define C_EMBD 1024
#define T_SEQ  2048
#define N_BATCH 2
#define N_HEADS 16
#define HEAD_D 64
#define M_TOK  4096   // N_BATCH * T_SEQ
#define Q_SCALE 0.18033688011112042f  // 1/sqrt(64) * log2(e)

__device__ __forceinline__ u16 f2b(float f) {
  union { float f; unsigned u; } v; v.f = f;
  unsigned r = (v.u + 0x7fffu + ((v.u >> 16) & 1u)) >> 16;  // RNE
  return (u16)r;
}
__device__ __forceinline__ float b2f(u16 u) {
  union { unsigned u; float f; } v; v.u = ((unsigned)u) << 16;
  return v.f;
}
// pack 2 fp32 -> bf16x2 by truncation: lo16 = a.hi16, hi16 = b.hi16 (1 VALU op)
__device__ __forceinline__ unsigned pk2(float a, float b) {
  union { float f; unsigned u; } x, y; x.f = a; y.f = b;
  return __builtin_amdgcn_perm(y.u, x.u, 0x07060302u);
}
__device__ __forceinline__ void load_lds16(const void* g, void* l) {
  __builtin_amdgcn_global_load_lds(
      (const __attribute__((address_space(1))) void*)g,
      (__attribute__((address_space(3))) void*)l, 16, 0, 0);
}
// tanh-form GELU in exp2 domain: x * t/(t+1), t = exp2(2.3021859*(x+0.044715x^3))
__device__ __forceinline__ float gelu_fast(float x) {
  const float p = x * __builtin_fmaf(0.044715f * x, x, 1.0f);
  const float t = __builtin_amdgcn_exp2f(2.3021859215f * p);
  return x * t * __builtin_amdgcn_rcpf(t + 1.0f);
}

// ---------------------------------------------------------------------------
// Fused weight transpose + cast for all 4 weights: W[K][N] fp32 -> Wt[N][K] bf16
// ---------------------------------------------------------------------------
__global__ __launch_bounds__(256) void transpose_cast_all(
    const float* __restrict__ W0, u16* __restrict__ D0,   // attn 1024x3072
    const float* __restrict__ W1, u16* __restrict__ D1,   // proj 1024x1024
    const float* __restrict__ W2, u16* __restrict__ D2,   // fc   1024x4096
    const float* __restrict__ W3, u16* __restrict__ D3) { // fc2  4096x1024
  int id = blockIdx.x;
  const float* W; u16* D; int K, N, t;
  if (id < 3072)      { W = W0; D = D0; K = 1024; N = 3072; t = id; }
  else if (id < 4096) { W = W1; D = D1; K = 1024; N = 1024; t = id - 3072; }
  else if (id < 8192) { W = W2; D = D2; K = 1024; N = 4096; t = id - 4096; }
  else                { W = W3; D = D3; K = 4096; N = 1024; t = id - 8192; }
  const int nTN = N >> 5;
  const int n0 = (t % nTN) * 32, k0 = (t / nTN) * 32;
  __shared__ float tile[32][33];
  const int tx = threadIdx.x & 31, ty = threadIdx.x >> 5;  // ty in [0,8)
#pragma unroll
  for (int i = 0; i < 32; i += 8)
    tile[ty + i][tx] = W[(size_t)(k0 + ty + i) * N + n0 + tx];
  __syncthreads();
#pragma unroll
  for (int i = 0; i < 32; i += 8)
    D[(size_t)(n0 + ty + i) * K + k0 + tx] = f2b(tile[tx][ty + i]);
}

// ---------------------------------------------------------------------------
// LayerNorm over rows of 1024 fp32 -> bf16 out. One block (256 thr) per row.
// ---------------------------------------------------------------------------
__global__ __launch_bounds__(256) void ln_cast(
    const float* __restrict__ X, const float* __restrict__ g,
    const float* __restrict__ b, u16* __restrict__ Y) {
  const int row = blockIdx.x;
  const int tid = threadIdx.x;
  const float4 v = ((const float4*)(X + (size_t)row * C_EMBD))[tid];
  float s = v.x + v.y + v.z + v.w;
  float ss = v.x * v.x + v.y * v.y + v.z * v.z + v.w * v.w;
#pragma unroll
  for (int off = 32; off > 0; off >>= 1) {
    s += __shfl_down(s, off, 64);
    ss += __shfl_down(ss, off, 64);
  }
  __shared__ float red[8];
  __shared__ float stats[2];
  const int wave = tid >> 6, lane = tid & 63;
  if (lane == 0) { red[wave] = s; red[4 + wave] = ss; }
  __syncthreads();
  if (tid == 0) {
    float S = red[0] + red[1] + red[2] + red[3];
    float SS = red[4] + red[5] + red[6] + red[7];
    float mu = S * (1.0f / C_EMBD);
    float var = SS * (1.0f / C_EMBD) - mu * mu;
    stats[0] = mu;
    stats[1] = rsqrtf(var + 1e-5f);
  }
  __syncthreads();
  const float mu = stats[0], rs = stats[1];
  const float4 gv = ((const float4*)g)[tid];
  const float4 bv = ((const float4*)b)[tid];
  ushort4 o;
  o.x = f2b((v.x - mu) * rs * gv.x + bv.x);
  o.y = f2b((v.y - mu) * rs * gv.y + bv.y);
  o.z = f2b((v.z - mu) * rs * gv.z + bv.z);
  o.w = f2b((v.w - mu) * rs * gv.w + bv.w);
  ((ushort4*)(Y + (size_t)row * C_EMBD))[tid] = o;
}

// ---------------------------------------------------------------------------
// Fused: x1 = P0 + P1 + bias + res, then LayerNorm(x1) -> bf16 Y.
// ---------------------------------------------------------------------------
__global__ __launch_bounds__(256) void ln_reduce_cast(
    const float* __restrict__ P0, const float* __restrict__ P1,
    const float* __restrict__ bias, const float* __restrict__ res,
    const float* __restrict__ g, const float* __restrict__ b,
    float* __restrict__ X1, u16* __restrict__ Y) {
  const int row = blockIdx.x;
  const int tid = threadIdx.x;
  const size_t base = (size_t)row * C_EMBD;
  const float4 p0 = ((const float4*)(P0 + base))[tid];
  const float4 p1 = ((const float4*)(P1 + base))[tid];
  const float4 rr = ((const float4*)(res + base))[tid];
  const float4 bb = ((const float4*)bias)[tid];
  float4 v;
  v.x = p0.x + p1.x + rr.x + bb.x;
  v.y = p0.y + p1.y + rr.y + bb.y;
  v.z = p0.z + p1.z + rr.z + bb.z;
  v.w = p0.w + p1.w + rr.w + bb.w;
  ((float4*)(X1 + base))[tid] = v;
  float s = v.x + v.y + v.z + v.w;
  float ss = v.x * v.x + v.y * v.y + v.z * v.z + v.w * v.w;
#pragma unroll
  for (int off = 32; off > 0; off >>= 1) {
    s += __shfl_down(s, off, 64);
    ss += __shfl_down(ss, off, 64);
  }
  __shared__ float red[8];
  __shared__ float stats[2];
  const int wave = tid >> 6, lane = tid & 63;
  if (lane == 0) { red[wave] = s; red[4 + wave] = ss; }
  __syncthreads();
  if (tid == 0) {
    float S = red[0] + red[1] + red[2] + red[3];
    float SS = red[4] + red[5] + red[6] + red[7];
    float mu = S * (1.0f / C_EMBD);
    float var = SS * (1.0f / C_EMBD) - mu * mu;
    stats[0] = mu;
    stats[1] = rsqrtf(var + 1e-5f);
  }
  __syncthreads();
  const float mu = stats[0], rs = stats[1];
  const float4 gv = ((const float4*)g)[tid];
  const float4 bv = ((const float4*)b)[tid];
  ushort4 o;
  o.x = f2b((v.x - mu) * rs * gv.x + bv.x);
  o.y = f2b((v.y - mu) * rs * gv.y + bv.y);
  o.z = f2b((v.z - mu) * rs * gv.z + bv.z);
  o.w = f2b((v.w - mu) * rs * gv.w + bv.w);
  ((ushort4*)(Y + base))[tid] = o;
}

enum { EPI_BF16 = 0, EPI_GELU_BF16 = 2, EPI_PART = 3, EPI_QKV = 4 };

// ---------------------------------------------------------------------------
// OLD 128x128 GEMM (2-barrier structure) — kept for proj only (split-K=2).
// ---------------------------------------------------------------------------
template <int EPI, int SPLIT>
__global__ __launch_bounds__(256) void gemm_bt(
    const u16* __restrict__ A, const u16* __restrict__ Bt,
    const float* __restrict__ bias,
    void* __restrict__ Cout, void* __restrict__ Cout2, void* __restrict__ Cout3,
    int M, int N, int K) {
  __shared__ u16 As[128 * 64];
  __shared__ u16 Bs[128 * 64];
  const int tid = threadIdx.x;
  const int wave = tid >> 6, lane = tid & 63;
  const int quad = lane >> 4, l16 = lane & 15;
  const int sw = l16 & 7;

  const int id = (int)blockIdx.y * (int)gridDim.x + (int)blockIdx.x;
  const int mt = ((id & 7) << 2) + ((id >> 3) & 3);
  const int nt_ = id >> 5;
  const int m0 = mt * 128, n0 = nt_ * 128;

  const int wm = (wave >> 1) * 64, wn = (wave & 1) * 64;

  f32x4 acc[4][4] = {};

  size_t aOff[4], bOff[4];
  int ldsOff[4];
#pragma unroll
  for (int i = 0; i < 4; ++i) {
    const int c = tid + i * 256;
    const int row = c >> 3, gc = ((c & 7) ^ (row & 7)) * 8;
    aOff[i] = (size_t)(m0 + row) * K + gc;
    bOff[i] = (size_t)(n0 + row) * K + gc;
    ldsOff[i] = c * 8;
  }

  const int kTiles = (K >> 6) / SPLIT;
  const int kt0 = (SPLIT == 2) ? (int)blockIdx.z * kTiles : 0;
  for (int kt = kt0; kt < kt0 + kTiles; ++kt) {
    const int k0 = kt << 6;
#pragma unroll
    for (int i = 0; i < 4; ++i)
      load_lds16(A + aOff[i] + k0, &As[ldsOff[i]]);
#pragma unroll
    for (int i = 0; i < 4; ++i)
      load_lds16(Bt + bOff[i] + k0, &Bs[ldsOff[i]]);
    __syncthreads();
#pragma unroll
    for (int ks = 0; ks < 2; ++ks) {
      bf16x8 aF[4], bF[4];
#pragma unroll
      for (int t = 0; t < 4; ++t) {
        aF[t] = *(const bf16x8*)
            &As[(wm + t * 16 + l16) * 64 + (((ks * 4 + quad) ^ sw) * 8)];
        bF[t] = *(const bf16x8*)
            &Bs[(wn + t * 16 + l16) * 64 + (((ks * 4 + quad) ^ sw) * 8)];
      }
#pragma unroll
      for (int tm = 0; tm < 4; ++tm)
#pragma unroll
        for (int tn = 0; tn < 4; ++tn)
          acc[tm][tn] = __builtin_amdgcn_mfma_f32_16x16x32_bf16(
              bF[tn], aF[tm], acc[tm][tn], 0, 0, 0);  // transposed: C^T
    }
    __syncthreads();
  }

  float* Pz = (float*)((SPLIT == 2 && blockIdx.z == 1) ? Cout2 : Cout);
#pragma unroll
  for (int tm = 0; tm < 4; ++tm) {
    const int row = m0 + wm + tm * 16 + l16;
#pragma unroll
    for (int tn = 0; tn < 4; ++tn) {
      const int col = n0 + wn + tn * 16 + quad * 4;
      if constexpr (EPI == EPI_PART) {
        *(float4*)&Pz[(size_t)row * N + col] = *(float4*)&acc[tm][tn];
      } else {
        const float4 bz = *(const float4*)&bias[col];
        float v0 = acc[tm][tn][0] + bz.x, v1 = acc[tm][tn][1] + bz.y;
        float v2 = acc[tm][tn][2] + bz.z, v3 = acc[tm][tn][3] + bz.w;
        if constexpr (EPI == EPI_GELU_BF16) {
          v0 = gelu_fast(v0); v1 = gelu_fast(v1);
          v2 = gelu_fast(v2); v3 = gelu_fast(v3);
        }
        ushort4 o;
        o.x = f2b(v0); o.y = f2b(v1); o.z = f2b(v2); o.w = f2b(v3);
        *(ushort4*)&((u16*)Cout)[(size_t)row * N + col] = o;
      }
    }
  }
}

// ---------------------------------------------------------------------------
// 256x256 8-phase GEMM (R10 schedule, verified 788 TF). 512 thr / 8 waves
// (2Mx4N), BK=64, 128 KiB LDS, 8 half-tile slots double-buffered by parity.
// Phase order (0,0)(0,1)(1,0)(1,1) with fragment carry:
//   P1 reads A0(8)+B0(4); P2 reads B1(4); P3 reads A1(8); P4 reads 0.
// Phase = {ds_reads; 1 stage; barrier; lgkmcnt(0); setprio(1); 16 MFMA;
//          setprio(0); [vm4 at P4]; barrier}.
// Ledger: after each P4 vmcnt(4): exactly {A0,B0}(t+2) in flight; next 4
// phases add 8 loads; vmcnt(4) retires the 4 parity half-tiles of tile t+2
// exactly before their reads. Never vmcnt(0) in loop.
// R12: serpentine per-XCD L2-resident mapping (FETCH 78->27 MB measured).
// ---------------------------------------------------------------------------
#define G_LOADA(MQ, PAR)                                                      \
  { const u16* Ab_ = &lds[(unsigned)((((MQ)*2 + (PAR))) << 13)];              \
    _Pragma("unroll") for (int t_ = 0; t_ < 4; ++t_)                          \
      _Pragma("unroll") for (int ks = 0; ks < 2; ++ks)                        \
        aF[t_][ks] = *(const bf16x8*)&Ab_[(wm * 64 + t_ * 16 + l16) * 64 +    \
                                          (((ks * 4 + quad) ^ sw) << 3)]; }
#define G_LOADB(BV, NQ, PAR)                                                  \
  { const u16* Bb_ = &lds[(unsigned)(((2 + (NQ)) * 2 + (PAR)) << 13)];        \
    _Pragma("unroll") for (int u_ = 0; u_ < 2; ++u_)                          \
      _Pragma("unroll") for (int ks = 0; ks < 2; ++ks)                        \
        BV[u_][ks] = *(const bf16x8*)&Bb_[(wn * 32 + u_ * 16 + l16) * 64 +    \
                                          (((ks * 4 + quad) ^ sw) << 3)]; }
#define G_MMA(MQ, NQ, BV)                                                     \
    _Pragma("unroll") for (int t_ = 0; t_ < 4; ++t_)                          \
      _Pragma("unroll") for (int u_ = 0; u_ < 2; ++u_)                        \
        _Pragma("unroll") for (int ks = 0; ks < 2; ++ks)                      \
          acc[(MQ)*4 + t_][(NQ)*2 + u_] =                                     \
              __builtin_amdgcn_mfma_f32_16x16x32_bf16(                        \
                  BV[u_][ks], aF[t_][ks], acc[(MQ)*4 + t_][(NQ)*2 + u_],      \
                  0, 0, 0);
#define G_BAR()   __builtin_amdgcn_s_barrier()
#define G_LGKM0() asm volatile("s_waitcnt lgkmcnt(0)" ::: "memory")
#define G_PRIO(x) __builtin_amdgcn_s_setprio(x)

template <int EPI, int SPLIT>
__global__ __launch_bounds__(512, 2) void gemm256(
    const u16* __restrict__ A, const u16* __restrict__ Bt,
    const float* __restrict__ bias,
    void* __restrict__ Cout, void* __restrict__ Cout2,
    void* __restrict__ Cout3, void* __restrict__ Cout4,
    int M, int N, int K) {
  __shared__ u16 lds[8 * 8192];  // 8 regions x 16 KB = 128 KiB
  const int tid = threadIdx.x;
  const int lane = tid & 63;
  const int wave = tid >> 6;
  const int quad = lane >> 4, l16 = lane & 15;
  const int sw = l16 & 7;
  const int wm = wave >> 2, wn = wave & 3;  // 2 x 4 wave grid; 128x64 / wave

  // L2-resident mapping: per-XCD super-tile of am x bn tiles (serpentine
  // ntl walk). Per-XCD K-slice footprint (am+bn)*32KB << 4MB L2; each A/B
  // slab is fetched from L3 once per XCD. Measured: FETCH 78 -> 27 MB (fc).
  const int nTM = M >> 8, nTN = N >> 8;
  const int xcd = (int)blockIdx.x & 7;
  const int s = (int)blockIdx.x >> 3;       // slot within XCD
  const int gn = (nTN >= 6) ? 2 : 1;        // XCD grid over (mt,ntl) chunks
  const int gm = 8 / gn;
  const int am = nTM / gm, bn = nTN / gn;
  const int bi = s / am;
  int ai = s % am;
  if (bi & 1) ai = am - 1 - ai;             // serpentine
  const int mt = (xcd % gm) * am + ai;
  const int ntl = (xcd / gm) * bn + bi;
  const int m0 = mt << 8, n0 = ntl << 8;

  f32x4 acc[8][4] = {};  // acc[TM][TN]: m = m0+wm*128+TM*16+l16,
                         //             n = n0+wn*64+TN*16+quad*4+r

  // staging geometry: chunk c -> LDS row c>>3, source col chunk (c&7)^(r&7)
  size_t aOffs[2][2], bOffs[2][2];
  int ldsc[2];
#pragma unroll
  for (int i = 0; i < 2; ++i) {
    const int c = tid + i * 512;
    const int r = c >> 3;
    const int scc = ((c & 7) ^ (r & 7)) << 3;
    ldsc[i] = c * 8;
    const int ra = ((r >> 6) << 7) + (r & 63);  // A: X rows {0-63,128-191}
    const int rb = ((r >> 5) << 6) + (r & 31);  // B: quadrant-major rows
    aOffs[0][i] = (size_t)(m0 + ra) * K + scc;
    aOffs[1][i] = (size_t)(m0 + ra + 64) * K + scc;
    bOffs[0][i] = (size_t)(n0 + rb) * K + scc;
    bOffs[1][i] = (size_t)(n0 + rb + 32) * K + scc;
  }
  auto stA = [&](int mq, int p, int kt) {
    u16* dst = &lds[(size_t)((mq * 2 + p) << 13)];
    const int k0 = kt << 6;
#pragma unroll
    for (int i = 0; i < 2; ++i)
      load_lds16(A + aOffs[mq][i] + k0, dst + ldsc[i]);
  };
  auto stB = [&](int nq, int p, int kt) {
    u16* dst = &lds[(size_t)(((2 + nq) * 2 + p) << 13)];
    const int k0 = kt << 6;
#pragma unroll
    for (int i = 0; i < 2; ++i)
      load_lds16(Bt + bOffs[nq][i] + k0, dst + ldsc[i]);
  };

  const int NT = (K >> 6) / SPLIT;  // 16 for all our shapes (even)
  const int kt0 = (SPLIT > 1) ? (int)blockIdx.z * NT : 0;

  // prologue: tile0 parity0 {A0,B0,A1,B1}, then tile1 parity1 {B0,A0}.
  // vmcnt(4) retires the first 4 stages (all of tile 0).
  stA(0, 0, kt0); stB(0, 0, kt0); stA(1, 0, kt0); stB(1, 0, kt0);
  stB(0, 1, kt0 + 1); stA(0, 1, kt0 + 1);
  asm volatile("s_waitcnt vmcnt(4)" ::: "memory");
  G_BAR();

  bf16x8 aF[4][2];              // carried A fragments (one M-half)
  bf16x8 bF0[2][2], bF1[2][2];  // carried B fragments (both N-quadrants)

  for (int t = 0; t < NT; t += 2) {
#pragma unroll
    for (int p = 0; p < 2; ++p) {
      const int par = p;
      const int k1 = kt0 + (t + 1 + p < NT ? t + 1 + p : 0);  // junk on wrap
      const int k2 = kt0 + (t + 2 + p < NT ? t + 2 + p : 0);
      // P1: quadrant (0,0). Read A0+B0. Stage A1(par^1, k1).
      G_LOADA(0, par); G_LOADB(bF0, 0, par);
      stA(1, par ^ 1, k1);
      G_BAR(); G_LGKM0(); G_PRIO(1); G_MMA(0, 0, bF0); G_PRIO(0); G_BAR();
      // P2: quadrant (0,1). Read B1 (A0 carried). Stage B1(par^1, k1).
      G_LOADB(bF1, 1, par);
      stB(1, par ^ 1, k1);
      G_BAR(); G_LGKM0(); G_PRIO(1); G_MMA(0, 1, bF1); G_PRIO(0); G_BAR();
      // P3: quadrant (1,0). Read A1 (B0 carried). Stage A0(par, k2).
      G_LOADA(1, par);
      stA(0, par, k2);
      G_BAR(); G_LGKM0(); G_PRIO(1); G_MMA(1, 0, bF0); G_PRIO(0); G_BAR();
      // P4: quadrant (1,1). No reads (A1,B1 carried). Stage B0(par, k2).
      stB(0, par, k2);
      G_BAR(); G_PRIO(1); G_MMA(1, 1, bF1); G_PRIO(0);
      asm volatile("s_waitcnt vmcnt(4)" ::: "memory");
      G_BAR();
    }
  }
  // drain LDS-DMA before epilogue
  asm volatile("s_waitcnt vmcnt(0)" ::: "memory");

  if constexpr (EPI == EPI_PART) {
    const int z = (SPLIT > 1) ? (int)blockIdx.z : 0;
    float* Pz = (float*)(z == 0 ? Cout : z == 1 ? Cout2
                                       : z == 2 ? Cout3 : Cout4);
#pragma unroll
    for (int tm = 0; tm < 8; ++tm) {
      const int row = m0 + wm * 128 + tm * 16 + l16;
#pragma unroll
      for (int tn = 0; tn < 4; ++tn) {
        const int col = n0 + wn * 64 + tn * 16 + quad * 4;
        *(float4*)&Pz[(size_t)row * N + col] = *(float4*)&acc[tm][tn];
      }
    }
  } else if constexpr (EPI == EPI_QKV) {
#pragma unroll
    for (int tm = 0; tm < 8; ++tm) {
      const int row = m0 + wm * 128 + tm * 16 + l16;
      const int bb = row >> 11, tt = row & (T_SEQ - 1);
#pragma unroll
      for (int tn = 0; tn < 4; ++tn) {
        const int col = n0 + wn * 64 + tn * 16 + quad * 4;
        const float4 bz = *(const float4*)&bias[col];
        float v0 = acc[tm][tn][0] + bz.x, v1 = acc[tm][tn][1] + bz.y;
        float v2 = acc[tm][tn][2] + bz.z, v3 = acc[tm][tn][3] + bz.w;
        const int sec = col >> 10;
        const int h = (col & 1023) >> 6, d4 = col & 63;
        const int bh = bb * N_HEADS + h;
        if (sec == 0) {                      // Q, pre-scaled
          ushort4 o;
          o.x = f2b(v0 * Q_SCALE); o.y = f2b(v1 * Q_SCALE);
          o.z = f2b(v2 * Q_SCALE); o.w = f2b(v3 * Q_SCALE);
          *(ushort4*)&((u16*)Cout)[((size_t)bh * T_SEQ + tt) * HEAD_D + d4] = o;
        } else if (sec == 1) {               // K
          ushort4 o;
          o.x = f2b(v0); o.y = f2b(v1); o.z = f2b(v2); o.w = f2b(v3);
          *(ushort4*)&((u16*)Cout2)[((size_t)bh * T_SEQ + tt) * HEAD_D + d4] = o;
        } else {                             // V^T: [bh][d][t]
          u16* vp = (u16*)Cout3 + ((size_t)bh * HEAD_D + d4) * T_SEQ + tt;
          vp[0] = f2b(v0); vp[T_SEQ] = f2b(v1);
          vp[2 * T_SEQ] = f2b(v2); vp[3 * T_SEQ] = f2b(v3);
        }
      }
    }
  } else {  // EPI_BF16 / EPI_GELU_BF16
#pragma unroll
    for (int tm = 0; tm < 8; ++tm) {
      const int row = m0 + wm * 128 + tm * 16 + l16;
#pragma unroll
      for (int tn = 0; tn < 4; ++tn) {
        const int col = n0 + wn * 64 + tn * 16 + quad * 4;
        const float4 bz = *(const float4*)&bias[col];
        float v0 = acc[tm][tn][0] + bz.x, v1 = acc[tm][tn][1] + bz.y;
        float v2 = acc[tm][tn][2] + bz.z, v3 = acc[tm][tn][3] + bz.w;
        if constexpr (EPI == EPI_GELU_BF16) {
          v0 = gelu_fast(v0); v1 = gelu_fast(v1);
          v2 = gelu_fast(v2); v3 = gelu_fast(v3);
        }
        ushort4 o;
        o.x = f2b(v0); o.y = f2b(v1); o.z = f2b(v2); o.w = f2b(v3);
        *(ushort4*)&((u16*)Cout)[(size_t)row * N + col] = o;
      }
    }
  }
}

// ---------------------------------------------------------------------------
// reduce4: out = P0 + P1 + P2 + P3 + bias[col] + res. float4 per thread.
// ---------------------------------------------------------------------------
__global__ __launch_bounds__(256) void reduce_add4(
    const float* __restrict__ P0, const float* __restrict__ P1,
    const float* __restrict__ P2, const float* __restrict__ P3,
    const float* __restrict__ bias, const float* __restrict__ res,
    float* __restrict__ out) {
  const int idx = blockIdx.x * 256 + threadIdx.x;  // float4 index
  const float4 a = ((const float4*)P0)[idx];
  const float4 b = ((const float4*)P1)[idx];
  const float4 c = ((const float4*)P2)[idx];
  const float4 d = ((const float4*)P3)[idx];
  const float4 r = ((const float4*)res)[idx];
  const float4 g = ((const float4*)bias)[idx & 255];  // 1024/4 = 256
  float4 o;
  o.x = a.x + b.x + c.x + d.x + r.x + g.x;
  o.y = a.y + b.y + c.y + d.y + r.y + g.y;
  o.z = a.z + b.z + c.z + d.z + r.z + g.z;
  o.w = a.w + b.w + c.w + d.w + r.w + g.w;
  ((float4*)out)[idx] = o;
}

// ---------------------------------------------------------------------------
// Flash attention (causal). 1024 single-q-tile blocks, heavy-qb-first per
// XCD; defer-max (THR=8); LDS 40960 B = 4 blocks/CU.
// ---------------------------------------------------------------------------
__global__ __launch_bounds__(256, 4) void attn_fwd(
    const u16* __restrict__ Q, const u16* __restrict__ Kb,
    const u16* __restrict__ Vt, u16* __restrict__ Y) {
  const int id = (int)blockIdx.x;
  const int xcd = id & 7, slot = id >> 3;
  const int bh = xcd + ((slot & 3) << 3);       // 4 heads per XCD
  const int qb = (T_SEQ / 64 - 1) - (slot >> 2);  // heavy blocks dispatch first
  const int tid = threadIdx.x;
  const int wave = tid >> 6, lane = tid & 63;
  const int quad = lane >> 4, l16 = lane & 15;
  const int sw = l16 & 7;  // xor-swizzle key for frag reads
  const u16* Qp = Q + (size_t)bh * T_SEQ * HEAD_D;
  const u16* Kp = Kb + (size_t)bh * T_SEQ * HEAD_D;
  const u16* Vp = Vt + (size_t)bh * HEAD_D * T_SEQ;

  __shared__ u16 Ks[2][64 * 64];   // 16 KB
  __shared__ u16 Vs[2][64 * 64];   // 16 KB
  __shared__ u16 Pl[4][16 * 64];   // 8 KB, xor-swizzled chunks

  // staging geometry (chunk c -> row c>>3, col8 (c&7)^(row&7))
  const int c1 = tid, c2 = tid + 256;
  const int r1 = c1 >> 3, g1 = ((c1 & 7) ^ (r1 & 7)) * 8;
  const int r2 = c2 >> 3, g2 = ((c2 & 7) ^ (r2 & 7)) * 8;
  const size_t kO1 = (size_t)r1 * HEAD_D + g1, kO2 = (size_t)r2 * HEAD_D + g2;
  const size_t vO1 = (size_t)r1 * T_SEQ + g1, vO2 = (size_t)r2 * T_SEQ + g2;
  u16* const dK1[2] = {&Ks[0][c1 * 8], &Ks[1][c1 * 8]};
  u16* const dK2[2] = {&Ks[0][c2 * 8], &Ks[1][c2 * 8]};
  u16* const dV1[2] = {&Vs[0][c1 * 8], &Vs[1][c1 * 8]};
  u16* const dV2[2] = {&Vs[0][c2 * 8], &Vs[1][c2 * 8]};

  auto stageK = [&](int bb, int k0) {
    const u16* base = Kp + (size_t)k0 * HEAD_D;
    load_lds16(base + kO1, dK1[bb]);
    load_lds16(base + kO2, dK2[bb]);
  };
  auto stageV = [&](int bb, int k0) {
    const u16* base = Vp + k0;
    load_lds16(base + vO1, dV1[bb]);
    load_lds16(base + vO2, dV2[bb]);
  };

  const int b = bh >> 4, h = bh & 15;
  const int q0 = qb * 64;
  const int qglob = q0 + wave * 16 + l16;  // this lane's q row

  bf16x8 qF[2];
  qF[0] = *(const bf16x8*)&Qp[(size_t)qglob * HEAD_D + quad * 8];
  qF[1] = *(const bf16x8*)&Qp[(size_t)qglob * HEAD_D + 32 + quad * 8];

  f32x4 o[4] = {};   // O^T: d = nt*16 + quad*4 + r, q = l16
  float mrun = -3e38f, lrun = 0.0f;

  stageK(0, 0);
  stageV(0, 0);

  int buf = 0;
  for (int kb = 0; kb <= qb; ++kb) {
    const int k0 = kb * 64;
    __syncthreads();  // drains DMA + all waves' prior-buffer reads
    if (kb < qb) {
      stageK(buf ^ 1, k0 + 64);
      stageV(buf ^ 1, k0 + 64);
    }
    // S^T: key = nt*16 + quad*4 + r (rows), q = l16 (cols)
    f32x4 st[4] = {};
#pragma unroll
    for (int ks = 0; ks < 2; ++ks) {
#pragma unroll
      for (int nt = 0; nt < 4; ++nt) {
        bf16x8 kF = *(const bf16x8*)
            &Ks[buf][(nt * 16 + l16) * 64 + (((ks * 4 + quad) ^ sw) * 8)];
        st[nt] = __builtin_amdgcn_mfma_f32_16x16x32_bf16(kF, qF[ks], st[nt],
                                                         0, 0, 0);
      }
    }
    if (kb == qb) {  // causal mask, diagonal tile only
#pragma unroll
      for (int nt = 0; nt < 4; ++nt) {
#pragma unroll
        for (int r = 0; r < 4; ++r) {
          const int key = k0 + nt * 16 + quad * 4 + r;
          if (key > qglob) st[nt][r] = -3e38f;
        }
      }
    }
    // per-row tile max (register tree + cross-quad lanes ^16,^32)
    float m = st[0][0];
#pragma unroll
    for (int nt = 0; nt < 4; ++nt)
#pragma unroll
      for (int r = 0; r < 4; ++r) m = fmaxf(m, st[nt][r]);
    m = fmaxf(m, __shfl_xor(m, 16, 64));
    m = fmaxf(m, __shfl_xor(m, 32, 64));
    // defer-max (T13): skip rescale while growth <= 8 (P bounded by 2^8)
    if (!__all(m - mrun <= 8.0f)) {
      const float nm = fmaxf(mrun, m);
      const float alpha = __builtin_amdgcn_exp2f(mrun - nm);
      mrun = nm;
      lrun *= alpha;
#pragma unroll
      for (int nt = 0; nt < 4; ++nt)
#pragma unroll
        for (int r = 0; r < 4; ++r) o[nt][r] *= alpha;
    }
    float sum = 0.0f;
#pragma unroll
    for (int nt = 0; nt < 4; ++nt)
#pragma unroll
      for (int r = 0; r < 4; ++r) {
        const float p = __builtin_amdgcn_exp2f(st[nt][r] - mrun);
        st[nt][r] = p;
        sum += p;
      }
    sum += __shfl_xor(sum, 16, 64);
    sum += __shfl_xor(sum, 32, 64);
    lrun += sum;
    // P^T -> LDS (swizzled): logical col = key idx; chunk (col>>3) ^ sw
#pragma unroll
    for (int nt = 0; nt < 4; ++nt) {
      uint2 pk;
      pk.x = pk2(st[nt][0], st[nt][1]);
      pk.y = pk2(st[nt][2], st[nt][3]);
      const int wc = (((2 * nt + (quad >> 1)) ^ sw) << 3) + ((quad & 1) << 2);
      *(uint2*)&Pl[wave][(l16 << 6) + wc] = pk;
    }
    // O^T += V^T P^T  (A = V^T from Vs, B = P^T from Pl)
#pragma unroll
    for (int ks = 0; ks < 2; ++ks) {
      bf16x8 aP = *(const bf16x8*)
          &Pl[wave][(l16 << 6) + (((ks * 4 + quad) ^ sw) << 3)];
#pragma unroll
      for (int nt = 0; nt < 4; ++nt) {
        bf16x8 vF = *(const bf16x8*)
            &Vs[buf][(nt * 16 + l16) * 64 + (((ks * 4 + quad) ^ sw) * 8)];
        o[nt] =
            __builtin_amdgcn_mfma_f32_16x16x32_bf16(vF, aP, o[nt], 0, 0, 0);
      }
    }
    buf ^= 1;
  }

  // write O^T / l -> Y bf16 [B,T,C]: row = token (l16), cols = d
  const float rl = 1.0f / lrun;
  u16* yp = Y + ((size_t)(b * T_SEQ + qglob)) * C_EMBD + h * HEAD_D;
#pragma unroll
  for (int nt = 0; nt < 4; ++nt) {
    ushort4 ov;
    ov.x = f2b(o[nt][0] * rl); ov.y = f2b(o[nt][1] * rl);
    ov.z = f2b(o[nt][2] * rl); ov.w = f2b(o[nt][3] * rl);
    *(ushort4*)&yp[nt * 16 + quad * 4] = ov;
  }
}

// ---------------------------------------------------------------------------
// Host side. Workspace layout (unchanged): 48 MB contiguous region dead by
// fc2 time for 3 split-K partials.
// ---------------------------------------------------------------------------
extern "C" void kernel_launch(void* const* d_in, const int* in_sizes, int n_in,
                              void* d_out, int out_size, void* d_ws,
                              size_t ws_size, hipStream_t stream) {
  const float* x      = (const float*)d_in[0];
  const float* W_attn = (const float*)d_in[1];
  const float* b_attn = (const float*)d_in[2];
  const float* W_proj = (const float*)d_in[3];
  const float* b_proj = (const float*)d_in[4];
  const float* W_fc   = (const float*)d_in[5];
  const float* b_fc   = (const float*)d_in[6];
  const float* W_fc2  = (const float*)d_in[7];
  const float* b_fc2  = (const float*)d_in[8];
  const float* ln1_g  = (const float*)d_in[9];
  const float* ln1_b  = (const float*)d_in[10];
  const float* ln2_g  = (const float*)d_in[11];
  const float* ln2_b  = (const float*)d_in[12];

  u16* wfc2T = (u16*)d_ws;                              // [1024][4096] bf16
  float* x1  = (float*)(wfc2T + (size_t)1024 * 4096);   // [4096][1024] f32
  u16* hbuf  = (u16*)(x1 + (size_t)M_TOK * C_EMBD);     // [4096][4096] bf16
  u16* dead  = hbuf + (size_t)M_TOK * 4096;             // 48 MB dead-at-fc2
  u16* wqkvT = dead;                                    // [3072][1024]
  u16* wprojT = wqkvT + (size_t)3072 * 1024;            // [1024][1024]
  u16* wfcT  = wprojT + (size_t)1024 * 1024;            // [4096][1024]
  u16* Abuf  = wfcT + (size_t)4096 * 1024;              // [4096][1024] bf16
  u16* Qb    = Abuf + (size_t)M_TOK * C_EMBD;           // [32][2048][64]
  u16* Kbuf  = Qb + (size_t)32 * T_SEQ * HEAD_D;
  u16* Vtb   = Kbuf + (size_t)32 * T_SEQ * HEAD_D;

  float* projP = (float*)hbuf;            // proj partials 2x16MB (dead window)
  float* fc2P1 = (float*)dead;            // over wqkvT..wfcT   (16 MB)
  float* fc2P2 = fc2P1 + (size_t)M_TOK * C_EMBD;  // over Abuf..Qb (16 MB)
  float* fc2P3 = fc2P2 + (size_t)M_TOK * C_EMBD;  // over Kbuf..Vtb (16 MB)

  const dim3 blk(256);
  const dim3 blk512(512);

  transpose_cast_all<<<12288, blk, 0, stream>>>(
      W_attn, wqkvT, W_proj, wprojT, W_fc, wfcT, W_fc2, wfc2T);

  ln_cast<<<M_TOK, blk, 0, stream>>>(x, ln1_g, ln1_b, Abuf);

  // qkv: 256^2 8-phase, grid 8 XCD x (4x6) = 192
  gemm256<EPI_QKV, 1><<<dim3(192), blk512, 0, stream>>>(
      Abuf, wqkvT, b_attn, Qb, Kbuf, Vtb, nullptr, M_TOK, 3072, 1024);

  attn_fwd<<<dim3(1024), blk, 0, stream>>>(Qb, Kbuf, Vtb, Abuf);

  // proj: old 128^2 split-K=2 path (small GEMM; 256^2 can't fill the grid)
  gemm_bt<EPI_PART, 2><<<dim3(1024 / 128, M_TOK / 128, 2), blk, 0, stream>>>(
      Abuf, wprojT, nullptr, projP, projP + (size_t)M_TOK * C_EMBD, nullptr,
      M_TOK, 1024, 1024);
  ln_reduce_cast<<<M_TOK, blk, 0, stream>>>(
      projP, projP + (size_t)M_TOK * C_EMBD, b_proj, x, ln2_g, ln2_b,
      x1, Abuf);

  // fc: 256^2 8-phase, grid 8 x (4x8) = 256
  gemm256<EPI_GELU_BF16, 1><<<dim3(256), blk512, 0, stream>>>(
      Abuf, wfcT, b_fc, hbuf, nullptr, nullptr, nullptr, M_TOK, 4096, 1024);

  // fc2: 256^2 8-phase, split-K=4 -> grid 8 x (2x4) x 4z; f32 partials
  gemm256<EPI_PART, 4><<<dim3(64, 1, 4), blk512, 0, stream>>>(
      hbuf, wfc2T, nullptr, d_out, fc2P1, fc2P2, fc2P3, M_TOK, 1024, 4096);
  reduce_add4<<<M_TOK * C_EMBD / 1024, blk, 0, stream>>>(
      (const float*)d_out, fc2P1, fc2P2, fc2P3, b_fc2, x1, (float*)d_out);
}